// Round 2
// baseline (292.663 us; speedup 1.0000x reference)
//
#include <hip/hip_runtime.h>

#define C_IN 7
#define D_MODEL 512
#define KERNELS 73
#define MM 5
#define BBATCH 32
#define LL 4096
#define NTAP 18
#define TCHUNK 36                 // 2 t-slices of 18
#define XS_LD (TCHUNK + NTAP)     // 54 floats per channel; xs local l <-> t = T0-16+l
#define WINW (2 * NTAP)           // 36 preloaded window values per slice

__global__ __launch_bounds__(512) void tokemb_kernel(
    const float* __restrict__ x, const float* __restrict__ conv_w,
    const float* __restrict__ conv_b, const float* __restrict__ leftout_w,
    const float* __restrict__ leftout_b, float* __restrict__ out)
{
  __shared__ float xs[C_IN * XS_LD];   // 378 floats = 1.5 KB
  const int tid = threadIdx.x;
  const int b = blockIdx.y;
  const int T0 = blockIdx.x * TCHUNK;

  // Stage x[b, T0-16 .. T0+TCHUNK+1, :] (wrapped) into LDS, channel-major.
  const float* xb = x + (size_t)b * LL * C_IN;
  if (tid < C_IN * XS_LD) {
    const int c = tid / XS_LD;
    const int q = tid - c * XS_LD;
    int p = T0 - 16 + q;
    if (p < 0) p += LL;
    else if (p >= LL) p -= LL;
    xs[tid] = xb[p * C_IN + c];
  }

  // Thread -> (d-pair, t-slice).  Wave-uniform ts (waves 0-3: ts=0, 4-7: ts=1).
  const int dg = tid & 255;        // d-pair index, d0 = 2*dg
  const int ts = tid >> 8;         // t-slice 0/1
  const int d0 = dg * 2;
  const int d1 = d0 + 1;
  int ccA = d0 / KERNELS;                    // d0 <= 510 -> 0..6
  int ccB = d1 / KERNELS; if (ccB > C_IN - 1) ccB = C_IN - 1;  // d1=511 -> 6
  const bool leftB = (d1 == D_MODEL - 1);
  const int kkA = d0 - ccA * KERNELS;
  const int kkB = leftB ? 0 : (d1 - ccB * KERNELS);

  // FIR taps: out[t] = bias + sum_n wf[n] * x[t+1-n],  wf[n] = w[m=n/3][j=2-n%3]
  const float* wA = conv_w + kkA * (MM + 1) * 3;
  const float* wB = leftB ? leftout_w : (conv_w + kkB * (MM + 1) * 3);
  float wfA[NTAP], wfB[NTAP];
  #pragma unroll
  for (int n = 0; n < NTAP; ++n) {
    const int m = n / 3, j = 2 - (n % 3);
    wfA[n] = wA[m * 3 + j];
    wfB[n] = wB[m * 3 + j];
  }
  const float biasA = conv_b[kkA];
  const float biasB = leftB ? leftout_b[0] : conv_b[kkB];

  __syncthreads();

  // Preload full input window for this slice into registers (static indices).
  // xv[i] = x[(t0 - 16 + i) mod L]; output t0+u needs xv[u .. u+17].
  const int t0 = T0 + ts * NTAP;
  const int lbase = ts * NTAP;
  const float* pA = xs + ccA * XS_LD + lbase;
  const float* pB = xs + ccB * XS_LD + lbase;
  float xvA[WINW], xvB[WINW];
  #pragma unroll
  for (int i = 0; i < WINW; ++i) { xvA[i] = pA[i]; xvB[i] = pB[i]; }

  float2* o = reinterpret_cast<float2*>(out + ((size_t)b * LL + t0) * D_MODEL) + dg;

  if (t0 >= 16 && t0 + (NTAP - 1) <= LL - 2) {
    // Interior: pure 18-tap FIR, no masking, no wrap. Stall-free loop.
    #pragma unroll
    for (int u = 0; u < NTAP; ++u) {
      float a = biasA, c2 = biasB;
      #pragma unroll
      for (int n = 0; n < NTAP; ++n) {
        a  += xvA[u + 17 - n] * wfA[n];
        c2 += xvB[u + 17 - n] * wfB[n];
      }
      o[(size_t)u * (D_MODEL / 2)] = make_float2(a, c2);
    }
  } else {
    // Boundary: mask taps where uu = (t-1+j) mod L < 15 (zero-padded delay
    // embedding); skip stores for t >= L.  u must stay compile-time for the
    // register-array indices.
    #pragma unroll
    for (int u = 0; u < NTAP; ++u) {
      const int t = t0 + u;
      float a = biasA, c2 = biasB;
      #pragma unroll
      for (int j = 0; j < 3; ++j) {
        int uu = t - 1 + j;
        if (uu < 0) uu += LL;
        else if (uu >= LL) uu -= LL;
        if (uu >= 15) {
          #pragma unroll
          for (int m = 0; m <= MM; ++m) {
            const int n = 3 * m + 2 - j;
            a  += xvA[u + 17 - n] * wfA[n];
            c2 += xvB[u + 17 - n] * wfB[n];
          }
        }
      }
      if (t < LL) o[(size_t)u * (D_MODEL / 2)] = make_float2(a, c2);
    }
  }
}

extern "C" void kernel_launch(void* const* d_in, const int* in_sizes, int n_in,
                              void* d_out, int out_size, void* d_ws, size_t ws_size,
                              hipStream_t stream) {
  const float* x = (const float*)d_in[0];
  const float* conv_w = (const float*)d_in[1];
  const float* conv_b = (const float*)d_in[2];
  const float* leftout_w = (const float*)d_in[3];
  const float* leftout_b = (const float*)d_in[4];
  float* out = (float*)d_out;
  dim3 grid((LL + TCHUNK - 1) / TCHUNK, BBATCH);
  tokemb_kernel<<<grid, 512, 0, stream>>>(x, conv_w, conv_b, leftout_w, leftout_b, out);
}

// Round 3
// 287.153 us; speedup vs baseline: 1.0192x; 1.0192x over previous
//
#include <hip/hip_runtime.h>

#define C_IN 7
#define D_MODEL 512
#define KERNELS 73
#define MM 5
#define BBATCH 32
#define LL 4096
#define TCHUNK 72          // multiple of NTAP; ceil(4096/72)=57 t-blocks
#define NTAP 18
#define XS_LD (TCHUNK + NTAP)   // 90 floats per channel (16 halo before, 2 after)

__global__ __launch_bounds__(512) void tokemb_kernel(
    const float* __restrict__ x, const float* __restrict__ conv_w,
    const float* __restrict__ conv_b, const float* __restrict__ leftout_w,
    const float* __restrict__ leftout_b, float* __restrict__ out)
{
  __shared__ float xs[C_IN * XS_LD];
  const int tid = threadIdx.x;
  const int b = blockIdx.y;
  const int T0 = blockIdx.x * TCHUNK;

  // Stage x[b, T0-16 .. T0+TCHUNK+1, :] (wrapped) into LDS, channel-major.
  const float* xb = x + (size_t)b * LL * C_IN;
  for (int e = tid; e < C_IN * XS_LD; e += 512) {
    int c = e / XS_LD;
    int q = e - c * XS_LD;
    int p = T0 - 16 + q;
    if (p < 0) p += LL;
    else if (p >= LL) p -= LL;
    xs[e] = xb[p * C_IN + c];
  }

  // Per-thread FIR taps: wf[n] = w[k][m][j], m=n/3, j=2-(n%3)
  const int d = tid;
  const bool left = (d == D_MODEL - 1);
  int cc, kk;
  if (left) { cc = C_IN - 1; kk = 0; }
  else { cc = d / KERNELS; kk = d - cc * KERNELS; }
  const float* wsrc = left ? leftout_w : (conv_w + kk * (MM + 1) * 3);
  float wf[NTAP];
  #pragma unroll
  for (int n = 0; n < NTAP; ++n) {
    int m = n / 3, j = 2 - (n % 3);
    wf[n] = wsrc[m * 3 + j];
  }
  const float bias = left ? leftout_b[0] : conv_b[kk];

  __syncthreads();

  const float* xc = xs + cc * XS_LD;

  // Circular register window. Invariant before global sub-iter s = tl0+u:
  // phys p holds xs-index q with q ≡ p (mod 18), q ∈ [s, s+18).
  float win[NTAP];
  #pragma unroll
  for (int p = 0; p < NTAP; ++p) win[p] = xc[p];

  float* outb = out + ((size_t)b * LL + T0) * D_MODEL + d;

  for (int tl0 = 0; tl0 < TCHUNK; tl0 += NTAP) {
    const int tg = T0 + tl0;
    if (tg >= 16 && tg <= LL - 1 - NTAP) {
      // clean: all 18 t's fully interior -> pure FMA, zero moves
      #pragma unroll
      for (int u = 0; u < NTAP; ++u) {
        float acc = bias;
        #pragma unroll
        for (int n = 0; n < NTAP; ++n)
          acc += win[(u + 17 - n) % NTAP] * wf[n];
        __builtin_nontemporal_store(acc, &outb[(size_t)(tl0 + u) * D_MODEL]);
        win[u] = xc[tl0 + u + NTAP];   // xs index s+18 -> phys (s%18)==u
      }
    } else {
      // boundary: zero-padded delay embedding (uu<15) / circular edge / t>=LL
      #pragma unroll
      for (int u = 0; u < NTAP; ++u) {
        const int t = tg + u;
        float acc = bias;
        #pragma unroll
        for (int j = 0; j < 3; ++j) {
          int uu = t - 1 + j;
          if (uu < 0) uu += LL;
          else if (uu >= LL) uu -= LL;
          if (uu >= 15) {
            #pragma unroll
            for (int m = 0; m <= MM; ++m) {
              const int n = 3 * m + 2 - j;
              acc += win[(u + 17 - n) % NTAP] * wf[n];
            }
          }
        }
        if (t < LL) __builtin_nontemporal_store(acc, &outb[(size_t)(tl0 + u) * D_MODEL]);
        win[u] = xc[tl0 + u + NTAP];
      }
    }
  }
}

extern "C" void kernel_launch(void* const* d_in, const int* in_sizes, int n_in,
                              void* d_out, int out_size, void* d_ws, size_t ws_size,
                              hipStream_t stream) {
  const float* x = (const float*)d_in[0];
  const float* conv_w = (const float*)d_in[1];
  const float* conv_b = (const float*)d_in[2];
  const float* leftout_w = (const float*)d_in[3];
  const float* leftout_b = (const float*)d_in[4];
  float* out = (float*)d_out;
  dim3 grid((LL + TCHUNK - 1) / TCHUNK, BBATCH);
  tokemb_kernel<<<grid, 512, 0, stream>>>(x, conv_w, conv_b, leftout_w, leftout_b, out);
}